// Round 15
// baseline (183.054 us; speedup 1.0000x reference)
//
#include <hip/hip_runtime.h>

#define KP    96      // K=85 padded to 96 = 12 octets
#define NF    16
#define NCOL  117     // 16 + 85 + 16 output columns
#define PBLK  (KP * NF)   // 1536 floats per partial block
#define NPB   64      // points per block-iteration (k1): 32 lanes x 2 points
#define NB1   256     // k1 grid: 1 block/CU (12 waves; VGPR class caps at 16 waves/CU)

__device__ __forceinline__ float fast_exp2(float x) {
#if __has_builtin(__builtin_amdgcn_exp2f)
    return __builtin_amdgcn_exp2f(x);
#else
    float r;
    asm volatile("v_exp_f32 %0, %1" : "=v"(r) : "v"(x));
    return r;
#endif
}

// ---------------------------------------------------------------------------
// Kernel 1: wave-per-k-octet partial QF accumulation + last-block reduction.
// exp-diet: e = exp2(s*|x|^2 - x.qs + c), qs=2s*q, c=s*|q|^2 (5 insts/k,
// |x|^2 shared across k). Wave-uniform constants -> scalar regs.
// Last finished block (device atomic + threadfence, fixed-order sum ->
// deterministic) reduces partials and writes QF (omegaF applied).
// ---------------------------------------------------------------------------
__global__ __launch_bounds__(768, 3) void k1_partial(
    const float* __restrict__ X, const float* __restrict__ F,
    const float* __restrict__ QX, const float* __restrict__ omegaD,
    const float* __restrict__ omegaF,
    int K, int nchunk, int nb,
    float* __restrict__ partial, float* __restrict__ QF,
    int* __restrict__ counter)
{
    __shared__ __align__(16) float red[12 * 2 * 64];   // 6 KB
    __shared__ int is_last;

    const int tid  = threadIdx.x;
    const int lane = tid & 63;
    const int oct  = __builtin_amdgcn_readfirstlane(tid >> 6);
    const int fh   = lane >> 5;
    const int pl   = lane & 31;

    // per-k constants: {qs0, qs1, qs2, c} and s  (wave-uniform)
    float4 qreg[8];
    float  sreg[8];
#pragma unroll
    for (int kk = 0; kk < 8; ++kk) {
        const int k = oct * 8 + kk;
        float4 v = make_float4(0.f, 0.f, 0.f, -3.0e8f);  // pad: h=c -> exp2 -> 0
        float  s = 0.f;
        if (k < K) {
            const float qx = QX[k * 3 + 0];
            const float qy = QX[k * 3 + 1];
            const float qz = QX[k * 3 + 2];
            const float w  = omegaD[k];
            s = 1.4426950408889634f / (w * w);   // log2(e)/w^2
            v.x = 2.f * s * qx;
            v.y = 2.f * s * qy;
            v.z = 2.f * s * qz;
            v.w = s * (qx * qx + qy * qy + qz * qz);
        }
        qreg[kk] = v;
        sreg[kk] = s;
    }

    float acc[8][8];
#pragma unroll
    for (int a2 = 0; a2 < 8; ++a2)
#pragma unroll
        for (int b2 = 0; b2 < 8; ++b2) acc[a2][b2] = 0.f;

    int pb = blockIdx.x;
    float ax0 = 0.f, ax1 = 0.f, ax2 = 0.f, bx0 = 0.f, bx1 = 0.f, bx2 = 0.f;
    float4 faA = make_float4(0.f, 0.f, 0.f, 0.f), fbA = faA, faB = faA, fbB = faA;
    if (pb < nchunk) {
        const int pA = pb * NPB + pl, pB = pA + 32;
        ax0 = X[pA * 3 + 0]; ax1 = X[pA * 3 + 1]; ax2 = X[pA * 3 + 2];
        bx0 = X[pB * 3 + 0]; bx1 = X[pB * 3 + 1]; bx2 = X[pB * 3 + 2];
        faA = *reinterpret_cast<const float4*>(&F[(size_t)pA * NF + 8 * fh]);
        fbA = *reinterpret_cast<const float4*>(&F[(size_t)pA * NF + 8 * fh + 4]);
        faB = *reinterpret_cast<const float4*>(&F[(size_t)pB * NF + 8 * fh]);
        fbB = *reinterpret_cast<const float4*>(&F[(size_t)pB * NF + 8 * fh + 4]);
    }
    while (pb < nchunk) {
        const int pn = pb + gridDim.x;
        float nax0 = 0.f, nax1 = 0.f, nax2 = 0.f, nbx0 = 0.f, nbx1 = 0.f, nbx2 = 0.f;
        float4 nfaA = make_float4(0.f, 0.f, 0.f, 0.f), nfbA = nfaA, nfaB = nfaA, nfbB = nfaA;
        if (pn < nchunk) {
            const int pA = pn * NPB + pl, pB = pA + 32;
            nax0 = X[pA * 3 + 0]; nax1 = X[pA * 3 + 1]; nax2 = X[pA * 3 + 2];
            nbx0 = X[pB * 3 + 0]; nbx1 = X[pB * 3 + 1]; nbx2 = X[pB * 3 + 2];
            nfaA = *reinterpret_cast<const float4*>(&F[(size_t)pA * NF + 8 * fh]);
            nfbA = *reinterpret_cast<const float4*>(&F[(size_t)pA * NF + 8 * fh + 4]);
            nfaB = *reinterpret_cast<const float4*>(&F[(size_t)pB * NF + 8 * fh]);
            nfbB = *reinterpret_cast<const float4*>(&F[(size_t)pB * NF + 8 * fh + 4]);
        }
        // point A
        {
            const float xn2 = ax0 * ax0 + ax1 * ax1 + ax2 * ax2;
            float e[8];
#pragma unroll
            for (int kk = 0; kk < 8; ++kk) {
                const float4 q = qreg[kk];
                float h = fmaf(xn2, sreg[kk], q.w);
                h = fmaf(-ax0, q.x, h);
                h = fmaf(-ax1, q.y, h);
                h = fmaf(-ax2, q.z, h);
                e[kk] = fast_exp2(h);
            }
            const float fv[8] = {faA.x, faA.y, faA.z, faA.w, fbA.x, fbA.y, fbA.z, fbA.w};
#pragma unroll
            for (int kk = 0; kk < 8; ++kk)
#pragma unroll
                for (int u = 0; u < 8; ++u) acc[kk][u] += e[kk] * fv[u];
        }
        // point B
        {
            const float xn2 = bx0 * bx0 + bx1 * bx1 + bx2 * bx2;
            float e[8];
#pragma unroll
            for (int kk = 0; kk < 8; ++kk) {
                const float4 q = qreg[kk];
                float h = fmaf(xn2, sreg[kk], q.w);
                h = fmaf(-bx0, q.x, h);
                h = fmaf(-bx1, q.y, h);
                h = fmaf(-bx2, q.z, h);
                e[kk] = fast_exp2(h);
            }
            const float fv[8] = {faB.x, faB.y, faB.z, faB.w, fbB.x, fbB.y, fbB.z, fbB.w};
#pragma unroll
            for (int kk = 0; kk < 8; ++kk)
#pragma unroll
                for (int u = 0; u < 8; ++u) acc[kk][u] += e[kk] * fv[u];
        }
        ax0 = nax0; ax1 = nax1; ax2 = nax2; faA = nfaA; fbA = nfbA;
        bx0 = nbx0; bx1 = nbx1; bx2 = nbx2; faB = nfaB; fbB = nfbB;
        pb = pn;
    }

#pragma unroll
    for (int m = 1; m <= 16; m <<= 1) {
#pragma unroll
        for (int a2 = 0; a2 < 8; ++a2)
#pragma unroll
            for (int b2 = 0; b2 < 8; ++b2)
                acc[a2][b2] += __shfl_xor(acc[a2][b2], m);
    }
    if (pl == 0) {
        float* rp = &red[oct * 128 + fh * 64];
#pragma unroll
        for (int a2 = 0; a2 < 8; ++a2) {
            *reinterpret_cast<float4*>(&rp[a2 * 8]) =
                make_float4(acc[a2][0], acc[a2][1], acc[a2][2], acc[a2][3]);
            *reinterpret_cast<float4*>(&rp[a2 * 8 + 4]) =
                make_float4(acc[a2][4], acc[a2][5], acc[a2][6], acc[a2][7]);
        }
    }
    __syncthreads();
    float* pbase = partial + (size_t)blockIdx.x * PBLK;
    for (int idx = tid; idx < PBLK; idx += 768) {
        const int o2 = idx >> 7, r = idx & 127, kk = r >> 4, f = r & 15;
        pbase[idx] = red[o2 * 128 + (f >> 3) * 64 + kk * 8 + (f & 7)];
    }

    // ---- last-block-done reduction -> QF ----
    __threadfence();                       // release partial writes (device scope)
    if (tid == 0) {
        const int old = atomicAdd(counter, 1);
        is_last = (old == nb - 1) ? 1 : 0;
    }
    __syncthreads();
    if (is_last) {
        __threadfence();                   // acquire other blocks' writes
        for (int idx = tid; idx < PBLK; idx += 768) {
            float s0 = 0.f, s1 = 0.f, s2 = 0.f, s3 = 0.f;
            int b = 0;
            for (; b + 3 < nb; b += 4) {
                s0 += partial[(size_t)(b + 0) * PBLK + idx];
                s1 += partial[(size_t)(b + 1) * PBLK + idx];
                s2 += partial[(size_t)(b + 2) * PBLK + idx];
                s3 += partial[(size_t)(b + 3) * PBLK + idx];
            }
            for (; b < nb; ++b) s0 += partial[(size_t)b * PBLK + idx];
            const float s = (s0 + s1) + (s2 + s3);
            QF[idx] = s * omegaF[idx & 15];
        }
    }
}

// ---------------------------------------------------------------------------
// Kernel 2: double-buffered 32-row LDS stages + in-block B2 (R14 structure).
// ---------------------------------------------------------------------------
__global__ __launch_bounds__(256, 4) void k2_out(
    const float* __restrict__ F, const float* __restrict__ QFb,
    float* __restrict__ out)
{
    __shared__ __align__(16) float row[2][32 * NCOL];
    __shared__ __align__(16) float qf[85 * 16];
    __shared__ float b2[256];

    const int tid = threadIdx.x;
    const int q = tid & 31, pp = tid >> 5;

    for (int i = tid; i < 85 * 16; i += 256) qf[i] = QFb[i];
    __syncthreads();
    {
        const int u = tid & 15, v = tid >> 4;
        float s = 0.f;
        for (int k = 0; k < 85; ++k) s += qf[k * 16 + v] * qf[k * 16 + u];
        b2[tid] = s;
    }
    __syncthreads();

    float qr[3][NF];
#pragma unroll
    for (int j = 0; j < 3; ++j) {
        const int k = q + 32 * j;
        if (k < 85) {
#pragma unroll
            for (int u2 = 0; u2 < NF; ++u2) qr[j][u2] = qf[k * 16 + u2];
        } else {
#pragma unroll
            for (int u2 = 0; u2 < NF; ++u2) qr[j][u2] = 0.f;
        }
    }
    float b2c[NF];
#pragma unroll
    for (int v = 0; v < NF; ++v) b2c[v] = b2[v * 16 + (q & 15)];

    const int chunk = blockIdx.x * 256;
#pragma unroll 2
    for (int st = 0; st < 8; ++st) {
        const int sbase = chunk + st * 32;
        float* bufp = row[st & 1];
        float fr[NF];
        {
            const float4* Fv = reinterpret_cast<const float4*>(F + (size_t)(sbase + pp) * NF);
            const float4 t0 = Fv[0], t1 = Fv[1], t2 = Fv[2], t3 = Fv[3];
            fr[0]=t0.x; fr[1]=t0.y; fr[2]=t0.z; fr[3]=t0.w;
            fr[4]=t1.x; fr[5]=t1.y; fr[6]=t1.z; fr[7]=t1.w;
            fr[8]=t2.x; fr[9]=t2.y; fr[10]=t2.z; fr[11]=t2.w;
            fr[12]=t3.x; fr[13]=t3.y; fr[14]=t3.z; fr[15]=t3.w;
        }
#pragma unroll
        for (int it = 0; it < 4; ++it) {
            float4 n0, n1, n2, n3;
            if (it < 3) {
                const float4* Fv = reinterpret_cast<const float4*>(
                    F + (size_t)(sbase + (it + 1) * 8 + pp) * NF);
                n0 = Fv[0]; n1 = Fv[1]; n2 = Fv[2]; n3 = Fv[3];
            }
            float* rp = &bufp[(it * 8 + pp) * NCOL];
#pragma unroll
            for (int j = 0; j < 3; ++j) {
                const int k = q + 32 * j;
                float t = 0.f;
#pragma unroll
                for (int u2 = 0; u2 < NF; ++u2) t += fr[u2] * qr[j][u2];
                if (k < 85) rp[16 + k] = t;
            }
            if (q == 0) {
#pragma unroll
                for (int u2 = 0; u2 < NF; ++u2) rp[u2] = fr[u2];
            }
            if (q < 16) {
                float g = 0.f;
#pragma unroll
                for (int v = 0; v < NF; ++v) g += fr[v] * b2c[v];
                rp[101 + q] = g;
            }
            if (it < 3) {
                fr[0]=n0.x; fr[1]=n0.y; fr[2]=n0.z; fr[3]=n0.w;
                fr[4]=n1.x; fr[5]=n1.y; fr[6]=n1.z; fr[7]=n1.w;
                fr[8]=n2.x; fr[9]=n2.y; fr[10]=n2.z; fr[11]=n2.w;
                fr[12]=n3.x; fr[13]=n3.y; fr[14]=n3.z; fr[15]=n3.w;
            }
        }
        __syncthreads();
        {
            float4* dst = reinterpret_cast<float4*>(out + (size_t)sbase * NCOL);
            const float4* src = reinterpret_cast<const float4*>(bufp);
            for (int t2 = tid; t2 < (32 * NCOL) / 4; t2 += 256) dst[t2] = src[t2];
        }
    }
}

// ---------------------------------------------------------------------------
extern "C" void kernel_launch(void* const* d_in, const int* in_sizes, int n_in,
                              void* d_out, int out_size, void* d_ws, size_t ws_size,
                              hipStream_t stream)
{
    const float* X      = (const float*)d_in[0];
    const float* F      = (const float*)d_in[1];
    const float* QX     = (const float*)d_in[2];
    const float* omegaD = (const float*)d_in[3];
    const float* omegaF = (const float*)d_in[4];
    float* out = (float*)d_out;

    const int M = in_sizes[0] / 3;       // 262144
    const int K = in_sizes[3];           // 85
    const int nchunk = M / NPB;          // 4096

    int nb = (int)((ws_size / sizeof(float) - PBLK - 16) / PBLK);
    if (nb > NB1) nb = NB1;              // 256 -> 1 block/CU (12 waves)
    if (nb > nchunk) nb = nchunk;
    if (nb < 1) nb = 1;

    float* partial = (float*)d_ws;
    float* QFbuf   = partial + (size_t)nb * PBLK;
    int*   counter = (int*)(QFbuf + PBLK);

    hipMemsetAsync(counter, 0, sizeof(int), stream);
    hipLaunchKernelGGL(k1_partial, dim3(nb), dim3(768), 0, stream,
                       X, F, QX, omegaD, omegaF, K, nchunk, nb,
                       partial, QFbuf, counter);
    hipLaunchKernelGGL(k2_out, dim3(M / 256), dim3(256), 0, stream,
                       F, QFbuf, out);
}

// Round 16
// 79.369 us; speedup vs baseline: 2.3064x; 2.3064x over previous
//
#include <hip/hip_runtime.h>

#define KP    96      // K=85 padded to 96 k-rows (6 waves x 16)
#define NF    16
#define NCOL  117     // 16 + 85 + 16 output columns
#define PBLK  (KP * NF)   // 1536 floats per partial block
#define NB1   1024    // k1 grid

typedef __attribute__((ext_vector_type(8))) short bf16x8;
typedef __attribute__((ext_vector_type(4))) float f32x4;

__device__ __forceinline__ float fast_exp2(float x) {
#if __has_builtin(__builtin_amdgcn_exp2f)
    return __builtin_amdgcn_exp2f(x);
#else
    float r;
    asm volatile("v_exp_f32 %0, %1" : "=v"(r) : "v"(x));
    return r;
#endif
}

__device__ __forceinline__ unsigned short f2bf(float f) {   // RNE f32->bf16
    unsigned int u = __float_as_uint(f);
    u += 0x7FFFu + ((u >> 16) & 1u);
    return (unsigned short)(u >> 16);
}

// ---------------------------------------------------------------------------
// Kernel 1 (MFMA): partial QF via v_mfma_f32_16x16x32_bf16.
// Per 32-point tile: QF_tile = E[96k x 32p] @ F[32p x 16f].
// Block = 384 thr = 6 waves; wave w owns k-rows w*16..w*16+15 (one MFMA
// D[16x16] acc per wave, 4 VGPRs). Lane fragment duties (m=lane&15, g=lane>>4):
//   A[m][g*8+i] = E(k=kbase+m, p=g*8+i)   computed in-lane: exp2(s|x|^2-x.qs+c)
//   B[g*8+i][m] = F[p][f=m]               from LDS fs[32][17] (2-way max, free)
//   D[g*4+r][m] -> partial[k=kbase+g*4+r][f=m]
// Any consistent k-slot labeling between A and B is dot-product-invariant,
// so only the m/n axis conventions matter (D layout HW-verified).
// bf16 inputs: rel err ~0.4% << threshold margin (~1000x).
// ---------------------------------------------------------------------------
__global__ __launch_bounds__(384) void k1_partial(
    const float* __restrict__ X, const float* __restrict__ F,
    const float* __restrict__ QX, const float* __restrict__ omegaD,
    int K, int ntile, float* __restrict__ partial)
{
    __shared__ float xs[4 * 32];     // x0 | x1 | x2 | xn2
    __shared__ float fs[32 * 17];    // F tile, padded rows

    const int tid  = threadIdx.x;
    const int lane = tid & 63;
    const int wv   = __builtin_amdgcn_readfirstlane(tid >> 6);  // 0..5
    const int kbase = wv * 16;
    const int m = lane & 15;         // k-row (A) / f-col (B,D)
    const int g = lane >> 4;         // point-chunk 0..3

    // per-lane k constants
    const int k = kbase + m;
    float qs0 = 0.f, qs1 = 0.f, qs2 = 0.f, cc = -3.0e8f, ss = 0.f;
    if (k < K) {
        const float qx = QX[k * 3 + 0];
        const float qy = QX[k * 3 + 1];
        const float qz = QX[k * 3 + 2];
        const float w  = omegaD[k];
        ss  = 1.4426950408889634f / (w * w);     // log2(e)/w^2
        qs0 = 2.f * ss * qx; qs1 = 2.f * ss * qy; qs2 = 2.f * ss * qz;
        cc  = ss * (qx * qx + qy * qy + qz * qz);
    }

    f32x4 acc = {0.f, 0.f, 0.f, 0.f};

    for (int t = blockIdx.x; t < ntile; t += gridDim.x) {
        const int pbase = t * 32;
        // stage F tile (coalesced; [32][17] pad)
        for (int idx = tid; idx < 512; idx += 384) {
            const int p = idx >> 4, n = idx & 15;
            fs[p * 17 + n] = F[(size_t)(pbase + p) * NF + n];
        }
        // stage X tile + |x|^2
        if (tid < 32) {
            const float x0 = X[(pbase + tid) * 3 + 0];
            const float x1 = X[(pbase + tid) * 3 + 1];
            const float x2 = X[(pbase + tid) * 3 + 2];
            xs[tid]      = x0;
            xs[32 + tid] = x1;
            xs[64 + tid] = x2;
            xs[96 + tid] = x0 * x0 + x1 * x1 + x2 * x2;
        }
        __syncthreads();

        bf16x8 afrag, bfrag;
#pragma unroll
        for (int i = 0; i < 8; ++i) {
            const int p = g * 8 + i;
            const float x0 = xs[p], x1 = xs[32 + p], x2 = xs[64 + p], xn2 = xs[96 + p];
            float h = fmaf(xn2, ss, cc);
            h = fmaf(-x0, qs0, h);
            h = fmaf(-x1, qs1, h);
            h = fmaf(-x2, qs2, h);
            const float e = fast_exp2(h);
            afrag[i] = (short)f2bf(e);
            bfrag[i] = (short)f2bf(fs[p * 17 + m]);
        }
        acc = __builtin_amdgcn_mfma_f32_16x16x32_bf16(afrag, bfrag, acc, 0, 0, 0);
        __syncthreads();
    }

    // write partials: D[row=g*4+r][col=m], row = k-local
    float* pb = partial + (size_t)blockIdx.x * PBLK;
#pragma unroll
    for (int r = 0; r < 4; ++r) {
        const int krow = kbase + g * 4 + r;
        pb[krow * NF + m] = acc[r];
    }
}

// ---------------------------------------------------------------------------
// Kernel 1.5: fixed-order reduction of partials -> QF (applies omegaF).
// (R12 binary.)
// ---------------------------------------------------------------------------
__global__ __launch_bounds__(256) void k1_reduce(
    const float* __restrict__ partial, const float* __restrict__ omegaF,
    int nb, float* __restrict__ QF)
{
    const int k = blockIdx.x, tid = threadIdx.x;
    const int f = tid & 15, g = tid >> 4;
    float s = 0.f;
    for (int b = g; b < nb; b += 16)
        s += partial[(size_t)b * PBLK + k * NF + f];
    __shared__ float red[16][17];
    red[g][f] = s;
    __syncthreads();
    if (tid < 16) {
        float t = 0.f;
#pragma unroll
        for (int g2 = 0; g2 < 16; ++g2) t += red[g2][tid];
        QF[k * NF + tid] = t * omegaF[tid];
    }
}

// ---------------------------------------------------------------------------
// Kernel 1.75: B2 = QF^T @ QF  [16,16]. (R12 binary.)
// ---------------------------------------------------------------------------
__global__ __launch_bounds__(256) void k1_b2(
    const float* __restrict__ QF, float* __restrict__ B2)
{
    __shared__ float qf[85 * 16];
    const int tid = threadIdx.x;
    for (int i = tid; i < 85 * 16; i += 256) qf[i] = QF[i];
    __syncthreads();
    const int u = tid & 15, v = tid >> 4;
    float s = 0.f;
    for (int k = 0; k < 85; ++k) s += qf[k * 16 + v] * qf[k * 16 + u];
    B2[v * 16 + u] = s;
}

// ---------------------------------------------------------------------------
// Kernel 2: double-buffered 32-row LDS stages (R12 binary).
// ---------------------------------------------------------------------------
__global__ __launch_bounds__(256, 4) void k2_out(
    const float* __restrict__ F, const float* __restrict__ QFb,
    const float* __restrict__ B2, float* __restrict__ out)
{
    __shared__ __align__(16) float row[2][32 * NCOL];
    const int tid = threadIdx.x;
    const int q = tid & 31, pp = tid >> 5;
    float qr[3][NF];
#pragma unroll
    for (int j = 0; j < 3; ++j) {
        const int k = q + 32 * j;
        if (k < 85) {
            const float4* qv = reinterpret_cast<const float4*>(QFb + (size_t)k * NF);
#pragma unroll
            for (int u2 = 0; u2 < 4; ++u2) {
                const float4 t4 = qv[u2];
                qr[j][4 * u2 + 0] = t4.x; qr[j][4 * u2 + 1] = t4.y;
                qr[j][4 * u2 + 2] = t4.z; qr[j][4 * u2 + 3] = t4.w;
            }
        } else {
#pragma unroll
            for (int u2 = 0; u2 < NF; ++u2) qr[j][u2] = 0.f;
        }
    }
    float b2c[NF];
#pragma unroll
    for (int v = 0; v < NF; ++v) b2c[v] = B2[v * 16 + (q & 15)];
    const int chunk = blockIdx.x * 256;
#pragma unroll 2
    for (int st = 0; st < 8; ++st) {
        const int sbase = chunk + st * 32;
        float* bufp = row[st & 1];
        float fr[NF];
        {
            const float4* Fv = reinterpret_cast<const float4*>(F + (size_t)(sbase + pp) * NF);
            const float4 t0 = Fv[0], t1 = Fv[1], t2 = Fv[2], t3 = Fv[3];
            fr[0]=t0.x; fr[1]=t0.y; fr[2]=t0.z; fr[3]=t0.w;
            fr[4]=t1.x; fr[5]=t1.y; fr[6]=t1.z; fr[7]=t1.w;
            fr[8]=t2.x; fr[9]=t2.y; fr[10]=t2.z; fr[11]=t2.w;
            fr[12]=t3.x; fr[13]=t3.y; fr[14]=t3.z; fr[15]=t3.w;
        }
#pragma unroll
        for (int it = 0; it < 4; ++it) {
            float4 n0, n1, n2, n3;
            if (it < 3) {
                const float4* Fv = reinterpret_cast<const float4*>(
                    F + (size_t)(sbase + (it + 1) * 8 + pp) * NF);
                n0 = Fv[0]; n1 = Fv[1]; n2 = Fv[2]; n3 = Fv[3];
            }
            float* rp = &bufp[(it * 8 + pp) * NCOL];
#pragma unroll
            for (int j = 0; j < 3; ++j) {
                const int k = q + 32 * j;
                float t = 0.f;
#pragma unroll
                for (int u2 = 0; u2 < NF; ++u2) t += fr[u2] * qr[j][u2];
                if (k < 85) rp[16 + k] = t;
            }
            if (q == 0) {
#pragma unroll
                for (int u2 = 0; u2 < NF; ++u2) rp[u2] = fr[u2];
            }
            if (q < 16) {
                float g = 0.f;
#pragma unroll
                for (int v = 0; v < NF; ++v) g += fr[v] * b2c[v];
                rp[101 + q] = g;
            }
            if (it < 3) {
                fr[0]=n0.x; fr[1]=n0.y; fr[2]=n0.z; fr[3]=n0.w;
                fr[4]=n1.x; fr[5]=n1.y; fr[6]=n1.z; fr[7]=n1.w;
                fr[8]=n2.x; fr[9]=n2.y; fr[10]=n2.z; fr[11]=n2.w;
                fr[12]=n3.x; fr[13]=n3.y; fr[14]=n3.z; fr[15]=n3.w;
            }
        }
        __syncthreads();
        {
            float4* dst = reinterpret_cast<float4*>(out + (size_t)sbase * NCOL);
            const float4* src = reinterpret_cast<const float4*>(bufp);
            for (int t2 = tid; t2 < (32 * NCOL) / 4; t2 += 256) dst[t2] = src[t2];
        }
    }
}

// ---------------------------------------------------------------------------
extern "C" void kernel_launch(void* const* d_in, const int* in_sizes, int n_in,
                              void* d_out, int out_size, void* d_ws, size_t ws_size,
                              hipStream_t stream)
{
    const float* X      = (const float*)d_in[0];
    const float* F      = (const float*)d_in[1];
    const float* QX     = (const float*)d_in[2];
    const float* omegaD = (const float*)d_in[3];
    const float* omegaF = (const float*)d_in[4];
    float* out = (float*)d_out;

    const int M = in_sizes[0] / 3;       // 262144
    const int K = in_sizes[3];           // 85
    const int ntile = M / 32;            // 8192

    int nb = (int)((ws_size / sizeof(float) - PBLK - 256) / PBLK);
    if (nb > NB1) nb = NB1;              // 1024 blocks (grid-stride over tiles)
    if (nb > ntile) nb = ntile;
    if (nb < 1) nb = 1;

    float* partial = (float*)d_ws;
    float* QFbuf   = partial + (size_t)nb * PBLK;
    float* B2buf   = QFbuf + PBLK;

    hipLaunchKernelGGL(k1_partial, dim3(nb), dim3(384), 0, stream,
                       X, F, QX, omegaD, K, ntile, partial);
    hipLaunchKernelGGL(k1_reduce, dim3(KP), dim3(256), 0, stream,
                       partial, omegaF, nb, QFbuf);
    hipLaunchKernelGGL(k1_b2, dim3(1), dim3(256), 0, stream,
                       QFbuf, B2buf);
    hipLaunchKernelGGL(k2_out, dim3(M / 256), dim3(256), 0, stream,
                       F, QFbuf, B2buf, out);
}